// Round 3
// baseline (3841.944 us; speedup 1.0000x reference)
//
#include <hip/hip_runtime.h>
#include <stdint.h>

#define NB 16
#define NN 1024
#define ND 256

typedef __bf16 bf16x8 __attribute__((ext_vector_type(8)));
typedef float f32x4 __attribute__((ext_vector_type(4)));

__device__ __forceinline__ unsigned short f2bf(float x){
  unsigned u = __builtin_bit_cast(unsigned, x);
  u += 0x7FFFu + ((u >> 16) & 1u);          // round-to-nearest-even
  return (unsigned short)(u >> 16);
}
__device__ __forceinline__ float bflo(unsigned u){ return __builtin_bit_cast(float, u << 16); }
__device__ __forceinline__ float bfhi(unsigned u){ return __builtin_bit_cast(float, u & 0xFFFF0000u); }

// ---------------- kernel 1: l2-normalize rows, cast to bf16 ----------------
__global__ __launch_bounds__(256) void norm_cast_kernel(
    const float* __restrict__ fA, const float* __restrict__ fB,
    unsigned short* __restrict__ Abf, unsigned short* __restrict__ Bbf)
{
  int task = blockIdx.x * 4 + (threadIdx.x >> 6);
  int lane = threadIdx.x & 63;
  const float* src = (task < NB*NN) ? fA : fB;
  unsigned short* dst = (task < NB*NN) ? Abf : Bbf;
  int row = (task < NB*NN) ? task : task - NB*NN;
  float4 x = ((const float4*)(src + (size_t)row*ND))[lane];
  float sq = x.x*x.x + x.y*x.y + x.z*x.z + x.w*x.w;
  #pragma unroll
  for (int off = 32; off > 0; off >>= 1) sq += __shfl_xor(sq, off);
  float s = rsqrtf(fmaxf(sq, 1e-12f));
  ushort4 o;
  o.x = f2bf(x.x*s); o.y = f2bf(x.y*s); o.z = f2bf(x.z*s); o.w = f2bf(x.w*s);
  ((ushort4*)(dst + (size_t)row*ND))[lane] = o;
}

// ---------------- kernel 2: S = A·B^T (bf16 MFMA), K = exp(5·clip(S)) ------
#define LDK 40   // padded LDS tile row (elements)

__global__ __launch_bounds__(256) void gemm_exp_kernel(
    const unsigned short* __restrict__ Abf, const unsigned short* __restrict__ Bbf,
    float* __restrict__ S, unsigned short* __restrict__ Kg)
{
  __shared__ __align__(16) unsigned short As[128*LDK];
  __shared__ __align__(16) unsigned short Bs[128*LDK];
  const int b = blockIdx.z;
  const int mbase = blockIdx.y * 128;
  const int nbase = blockIdx.x * 128;
  const int t = threadIdx.x;
  const int lane = t & 63;
  const int wave = t >> 6;
  const int wm = wave >> 1, wn = wave & 1;
  const int quad = lane >> 4, l16 = lane & 15;

  const unsigned short* Ab = Abf + (size_t)b*NN*ND;
  const unsigned short* Bb = Bbf + (size_t)b*NN*ND;

  f32x4 acc[4][4];
  #pragma unroll
  for (int i=0;i<4;i++)
    #pragma unroll
    for (int j=0;j<4;j++) acc[i][j] = (f32x4){0.f,0.f,0.f,0.f};

  for (int k0 = 0; k0 < ND; k0 += 32){
    __syncthreads();
    #pragma unroll
    for (int i=0;i<2;i++){
      int chunk = t + 256*i;
      int row = chunk >> 2, seg = chunk & 3;
      *(uint4*)(&As[row*LDK + seg*8]) = *(const uint4*)(Ab + (size_t)(mbase+row)*ND + k0 + seg*8);
      *(uint4*)(&Bs[row*LDK + seg*8]) = *(const uint4*)(Bb + (size_t)(nbase+row)*ND + k0 + seg*8);
    }
    __syncthreads();
    bf16x8 af[4], bg[4];
    #pragma unroll
    for (int i=0;i<4;i++){
      af[i] = *(const bf16x8*)(&As[(wm*64 + i*16 + l16)*LDK + quad*8]);
      bg[i] = *(const bf16x8*)(&Bs[(wn*64 + i*16 + l16)*LDK + quad*8]);
    }
    #pragma unroll
    for (int i=0;i<4;i++)
      #pragma unroll
      for (int j=0;j<4;j++)
        acc[i][j] = __builtin_amdgcn_mfma_f32_16x16x32_bf16(af[i], bg[j], acc[i][j], 0, 0, 0);
  }

  float* Sb = S + (size_t)b*NN*NN;
  unsigned short* Kb = Kg + (size_t)b*NN*NN;
  #pragma unroll
  for (int i=0;i<4;i++){
    #pragma unroll
    for (int j=0;j<4;j++){
      int n = nbase + wn*64 + j*16 + l16;
      #pragma unroll
      for (int v=0;v<4;v++){
        int m = mbase + wm*64 + i*16 + quad*4 + v;
        float sv = acc[i][j][v];
        Sb[(size_t)m*NN + n] = sv;
        float sc = fminf(fmaxf(sv, -3.f), 3.f);
        Kb[(size_t)m*NN + n] = f2bf(__expf(5.f*sc));
      }
    }
  }
}

// -------- L2-local exchange primitives (fast path) --------
// store_l2: plain store (CDNA vector L1 is write-through -> lands in L2).
// poll8: 8 loads with sc0 (L1-bypass, L2-hit) sharing one waitcnt.
__device__ __forceinline__ void store_l2(float* p, float x){
  __hip_atomic_store(p, x, __ATOMIC_RELAXED, __HIP_MEMORY_SCOPE_WORKGROUP);
}

__device__ __forceinline__ bool poll8(const float* base, unsigned voff, float thr, float& sum){
  float x0,x1,x2,x3,x4,x5,x6,x7; unsigned a;
  asm volatile(
    "v_mov_b32 %8, %9\n\t"
    "global_load_dword %0, %8, %10 sc0\n\t"
    "v_add_u32 %8, 0x1000, %8\n\t"
    "global_load_dword %1, %8, %10 sc0\n\t"
    "v_add_u32 %8, 0x1000, %8\n\t"
    "global_load_dword %2, %8, %10 sc0\n\t"
    "v_add_u32 %8, 0x1000, %8\n\t"
    "global_load_dword %3, %8, %10 sc0\n\t"
    "v_add_u32 %8, 0x1000, %8\n\t"
    "global_load_dword %4, %8, %10 sc0\n\t"
    "v_add_u32 %8, 0x1000, %8\n\t"
    "global_load_dword %5, %8, %10 sc0\n\t"
    "v_add_u32 %8, 0x1000, %8\n\t"
    "global_load_dword %6, %8, %10 sc0\n\t"
    "v_add_u32 %8, 0x1000, %8\n\t"
    "global_load_dword %7, %8, %10 sc0\n\t"
    "s_waitcnt vmcnt(0)"
    : "=&v"(x0),"=&v"(x1),"=&v"(x2),"=&v"(x3),
      "=&v"(x4),"=&v"(x5),"=&v"(x6),"=&v"(x7),"=&v"(a)
    : "v"(voff), "s"((uint64_t)(uintptr_t)base)
    : "memory");
  bool ok = (x0>thr)&(x1>thr)&(x2>thr)&(x3>thr)&(x4>thr)&(x5>thr)&(x6>thr)&(x7>thr);
  sum = ((x0+x1)+(x2+x3))+((x4+x5)+(x6+x7));
  return ok;
}

__device__ __forceinline__ bool poll16(const float* base, int t, float thr, float& sum){
  float s0, s1;
  bool o0 = poll8(base, (unsigned)(t*4), thr, s0);
  bool o1 = poll8(base, (unsigned)(t*4) + 8u*4096u, thr, s1);
  sum = s0 + s1;
  return o0 & o1;
}

// ---------------- kernel 3: persistent Sinkhorn, K register-resident -------
// 256 blocks x 1024 threads; block (b=blk&15, rb=blk>>4) owns rows
// [64rb,64rb+64) of batch b. Under round-robin blk%8 XCD dispatch this puts
// all 16 blocks of a batch on ONE XCD, whose L2 IS coherent across its CUs.
//
// FAST path (probed, never assumed): exchange column partials through the
// local L2 -- plain stores + sc0 loads, ~300cy RT instead of the ~1-3us
// agent-scope fabric RT that dominated rounds 0-2 (~13us/iter of sync).
// A 2-phase runtime probe (tokens 1.0 then 2.0, through the exact same
// store/load paths, with timeouts) verifies cross-block L2 visibility
// INCLUDING the stale-reread case; per-batch verdicts are exchanged via
// always-correct agent-scope ops and the fast path is taken only if all 16
// blocks passed. Any surprise degrades to the round-2 agent path.
// Protocol (both paths): data-as-flag slots (partials > 0), 3-buffer
// rotation, zero own slot of buffer (it-1) after poll success at it.
__global__ __launch_bounds__(1024) void sinkhorn_kernel(
    const unsigned short* __restrict__ Kg, float* __restrict__ P,
    float* __restrict__ slots, unsigned* __restrict__ verdict)
{
  __shared__ __align__(16) float v[NN];
  __shared__ __align__(16) float part[NN];
  __shared__ __align__(16) float u[64];
  __shared__ int bad;
  __shared__ int fastflag;

  const int blk = blockIdx.x;
  const int b  = blk & 15;   // XCD-local batch placement
  const int rb = blk >> 4;
  const int t = threadIdx.x;
  const int w = t >> 6;      // wave id: column chunk for row phase
  const int l = t & 63;      // lane: row id for row phase

  const unsigned short* Kgb = Kg + ((size_t)(b*NN + rb*64))*NN;

  // column slice: rows 0..63 of column t, packed 2 rows per u32
  unsigned kcol[32];
  #pragma unroll
  for (int k=0;k<32;k++){
    unsigned lo = Kgb[(size_t)(2*k)*NN + t];
    unsigned hi = Kgb[(size_t)(2*k+1)*NN + t];
    kcol[k] = lo | (hi << 16);
  }
  // row slice: row l, cols w*64 .. w*64+63
  unsigned krow[32];
  {
    const uint4* rs = (const uint4*)(Kgb + (size_t)l*NN + w*64);
    #pragma unroll
    for (int k=0;k<8;k++){
      uint4 q4 = rs[k];
      krow[4*k+0]=q4.x; krow[4*k+1]=q4.y; krow[4*k+2]=q4.z; krow[4*k+3]=q4.w;
    }
  }
  v[t] = 1.0f;                      // v0 = 1 (global normalize cancels)

  // ---------- runtime probe of L2-local cross-block visibility ----------
  float* sl_b = slots + (size_t)b*4*16*NN;       // [4 bufs][16 blocks][NN]
  float* probe_base = sl_b + (size_t)3*16*NN;    // buffer 3 = probe region
  {
    float dum;
    store_l2(probe_base + (size_t)rb*NN + t, 1.0f);
    bool ok = false;
    unsigned long long dl = __builtin_amdgcn_s_memrealtime() + 100000ull; // ~1ms
    for(;;){
      ok = poll16(probe_base, t, 0.5f, dum);
      if (ok) break;
      if (__builtin_amdgcn_s_memrealtime() > dl) break;
      __builtin_amdgcn_s_sleep(1);
    }
    if (ok){  // phase 2: update must be seen through a previously-read line
      store_l2(probe_base + (size_t)rb*NN + t, 2.0f);
      dl = __builtin_amdgcn_s_memrealtime() + 100000ull;
      for(;;){
        if (poll16(probe_base, t, 1.5f, dum)) break;
        if (__builtin_amdgcn_s_memrealtime() > dl){ ok = false; break; }
        __builtin_amdgcn_s_sleep(1);
      }
    }
    if (t == 0) bad = 0;
    __syncthreads();
    if (!ok) bad = 1;                 // benign LDS race, all write 1
    __syncthreads();
    if (t == 0){
      unsigned my = bad ? 2u : 1u;    // 1 = fast ok, 2 = fail (0 = absent)
      __hip_atomic_store(&verdict[b*16 + rb], my,
                         __ATOMIC_RELAXED, __HIP_MEMORY_SCOPE_AGENT);
      int f = 1;
      for(;;){
        bool pending = false; f = 1;
        for (int p=0;p<16;p++){
          unsigned x = __hip_atomic_load(&verdict[b*16 + p],
                                         __ATOMIC_RELAXED, __HIP_MEMORY_SCOPE_AGENT);
          if (x == 0u){ pending = true; break; }
          if (x != 1u) f = 0;
        }
        if (!pending) break;
        __builtin_amdgcn_s_sleep(8);
      }
      fastflag = f;
    }
    __syncthreads();
  }
  const bool fastf = (fastflag != 0);

  const float4* v4 = (const float4*)v;
  const float4* u4 = (const float4*)u;
  float* my_slot = sl_b + (size_t)rb*NN + t;     // + buf*16*NN

  int buf = 0;
  float vt = 1.0f;
  for (int it = 0; it < 101; it++){     // 100 scan steps + 1 final step
    // phase A: u = 1/(K v). Wave w covers cols [64w,64w+64) of row l.
    float rsum = 0.f;
    #pragma unroll
    for (int k=0;k<16;k++){
      float4 vv = v4[w*16 + k];         // wave-uniform -> broadcast, no conflict
      unsigned ka = krow[2*k], kb = krow[2*k+1];
      rsum += bflo(ka)*vv.x + bfhi(ka)*vv.y + bflo(kb)*vv.z + bfhi(kb)*vv.w;
    }
    part[w*64 + l] = rsum;              // bank = l%32 -> 2-way, free
    __syncthreads();
    if (t < 64){
      float s = 0.f;
      #pragma unroll
      for (int q=0;q<16;q++) s += part[q*64 + t];
      u[t] = 1.0f / s;
    }
    __syncthreads();
    // phase B: column partial over our 64 rows (u reads broadcast)
    float csum = 0.f;
    #pragma unroll
    for (int k=0;k<16;k++){
      float4 uu = u4[k];
      unsigned ka = kcol[2*k], kb = kcol[2*k+1];
      csum += bflo(ka)*uu.x + bfhi(ka)*uu.y + bflo(kb)*uu.z + bfhi(kb)*uu.w;
    }
    float cs;
    int prev = (buf == 0) ? 2 : buf - 1;
    if (fastf){
      // L2-local exchange: plain store + sc0 poll (data-as-flag)
      store_l2(my_slot + (size_t)buf*16*NN, csum);
      const float* base = sl_b + (size_t)buf*16*NN;
      for(;;){
        if (poll16(base, t, 0.0f, cs)) break;
        __builtin_amdgcn_s_sleep(1);
      }
      store_l2(my_slot + (size_t)prev*16*NN, 0.f);
    } else {
      // agent-scope fallback (round-2 protocol, always correct)
      __hip_atomic_store(my_slot + (size_t)buf*16*NN, csum,
                         __ATOMIC_RELAXED, __HIP_MEMORY_SCOPE_AGENT);
      const float* base = sl_b + (size_t)buf*16*NN + t;
      for (;;){
        float s0 = 0.f; bool ok = true;
        #pragma unroll
        for (int p=0;p<16;p++){
          float x = __hip_atomic_load(base + (size_t)p*NN,
                                      __ATOMIC_RELAXED, __HIP_MEMORY_SCOPE_AGENT);
          ok &= (x != 0.f);
          s0 += x;
        }
        if (ok){ cs = s0; break; }
        __builtin_amdgcn_s_sleep(1);
      }
      __hip_atomic_store(my_slot + (size_t)prev*16*NN, 0.f,
                         __ATOMIC_RELAXED, __HIP_MEMORY_SCOPE_AGENT);
    }
    vt = 1.0f / cs;
    v[t] = vt;
    buf = (buf == 2) ? 0 : buf + 1;
    __syncthreads();
  }

  // epilogue: P[row][t] = u[row]*K[row][t]*v[t]  (overwrites K overlay; safe)
  float* Pb = P + ((size_t)(b*NN + rb*64))*NN;
  #pragma unroll
  for (int k=0;k<16;k++){
    float4 uu = u4[k];
    unsigned ka = kcol[2*k], kb = kcol[2*k+1];
    Pb[(size_t)(4*k+0)*NN + t] = bflo(ka)*uu.x*vt;
    Pb[(size_t)(4*k+1)*NN + t] = bfhi(ka)*uu.y*vt;
    Pb[(size_t)(4*k+2)*NN + t] = bflo(kb)*uu.z*vt;
    Pb[(size_t)(4*k+3)*NN + t] = bfhi(kb)*uu.w*vt;
  }
}

extern "C" void kernel_launch(void* const* d_in, const int* in_sizes, int n_in,
                              void* d_out, int out_size, void* d_ws, size_t ws_size,
                              hipStream_t stream)
{
  const float* fA = (const float*)d_in[0];
  const float* fB = (const float*)d_in[1];
  float* Pout = (float*)d_out;                       // outputs: [P | Sij]
  float* Sout = Pout + (size_t)NB*NN*NN;
  unsigned short* Kg = (unsigned short*)d_out;       // bf16 K overlays P region

  unsigned short* Abf = (unsigned short*)d_ws;                          // 8 MB
  unsigned short* Bbf = Abf + (size_t)NB*NN*ND;                         // 8 MB
  float* slots = (float*)((char*)d_ws + (size_t)16*1024*1024);          // 4 MB
  unsigned* verdict = (unsigned*)(slots + (size_t)NB*4*16*NN);          // 1 KB

  // zero slot buffers (3 exchange + 1 probe) + verdicts
  hipMemsetAsync(slots, 0, (size_t)NB*4*16*NN*4 + (size_t)NB*16*4, stream);
  norm_cast_kernel<<<dim3(8192), dim3(256), 0, stream>>>(fA, fB, Abf, Bbf);
  gemm_exp_kernel<<<dim3(8,8,NB), dim3(256), 0, stream>>>(Abf, Bbf, Sout, Kg);
  sinkhorn_kernel<<<dim3(256), dim3(1024), 0, stream>>>(Kg, Pout, slots, verdict);
}

// Round 4
// 1909.719 us; speedup vs baseline: 2.0118x; 2.0118x over previous
//
#include <hip/hip_runtime.h>
#include <stdint.h>

#define NB 16
#define NN 1024
#define ND 256

typedef __bf16 bf16x8 __attribute__((ext_vector_type(8)));
typedef float f32x4 __attribute__((ext_vector_type(4)));

__device__ __forceinline__ unsigned short f2bf(float x){
  unsigned u = __builtin_bit_cast(unsigned, x);
  u += 0x7FFFu + ((u >> 16) & 1u);          // round-to-nearest-even
  return (unsigned short)(u >> 16);
}
__device__ __forceinline__ float bflo(unsigned u){ return __builtin_bit_cast(float, u << 16); }
__device__ __forceinline__ float bfhi(unsigned u){ return __builtin_bit_cast(float, u & 0xFFFF0000u); }

// ---------------- kernel 1: l2-normalize rows, cast to bf16 ----------------
__global__ __launch_bounds__(256) void norm_cast_kernel(
    const float* __restrict__ fA, const float* __restrict__ fB,
    unsigned short* __restrict__ Abf, unsigned short* __restrict__ Bbf)
{
  int task = blockIdx.x * 4 + (threadIdx.x >> 6);
  int lane = threadIdx.x & 63;
  const float* src = (task < NB*NN) ? fA : fB;
  unsigned short* dst = (task < NB*NN) ? Abf : Bbf;
  int row = (task < NB*NN) ? task : task - NB*NN;
  float4 x = ((const float4*)(src + (size_t)row*ND))[lane];
  float sq = x.x*x.x + x.y*x.y + x.z*x.z + x.w*x.w;
  #pragma unroll
  for (int off = 32; off > 0; off >>= 1) sq += __shfl_xor(sq, off);
  float s = rsqrtf(fmaxf(sq, 1e-12f));
  ushort4 o;
  o.x = f2bf(x.x*s); o.y = f2bf(x.y*s); o.z = f2bf(x.z*s); o.w = f2bf(x.w*s);
  ((ushort4*)(dst + (size_t)row*ND))[lane] = o;
}

// ---------------- kernel 2: S = A·B^T (bf16 MFMA), K = exp(5·clip(S)) ------
#define LDK 40   // padded LDS tile row (elements)

__global__ __launch_bounds__(256) void gemm_exp_kernel(
    const unsigned short* __restrict__ Abf, const unsigned short* __restrict__ Bbf,
    float* __restrict__ S, unsigned short* __restrict__ Kg)
{
  __shared__ __align__(16) unsigned short As[128*LDK];
  __shared__ __align__(16) unsigned short Bs[128*LDK];
  const int b = blockIdx.z;
  const int mbase = blockIdx.y * 128;
  const int nbase = blockIdx.x * 128;
  const int t = threadIdx.x;
  const int lane = t & 63;
  const int wave = t >> 6;
  const int wm = wave >> 1, wn = wave & 1;
  const int quad = lane >> 4, l16 = lane & 15;

  const unsigned short* Ab = Abf + (size_t)b*NN*ND;
  const unsigned short* Bb = Bbf + (size_t)b*NN*ND;

  f32x4 acc[4][4];
  #pragma unroll
  for (int i=0;i<4;i++)
    #pragma unroll
    for (int j=0;j<4;j++) acc[i][j] = (f32x4){0.f,0.f,0.f,0.f};

  for (int k0 = 0; k0 < ND; k0 += 32){
    __syncthreads();
    #pragma unroll
    for (int i=0;i<2;i++){
      int chunk = t + 256*i;
      int row = chunk >> 2, seg = chunk & 3;
      *(uint4*)(&As[row*LDK + seg*8]) = *(const uint4*)(Ab + (size_t)(mbase+row)*ND + k0 + seg*8);
      *(uint4*)(&Bs[row*LDK + seg*8]) = *(const uint4*)(Bb + (size_t)(nbase+row)*ND + k0 + seg*8);
    }
    __syncthreads();
    bf16x8 af[4], bg[4];
    #pragma unroll
    for (int i=0;i<4;i++){
      af[i] = *(const bf16x8*)(&As[(wm*64 + i*16 + l16)*LDK + quad*8]);
      bg[i] = *(const bf16x8*)(&Bs[(wn*64 + i*16 + l16)*LDK + quad*8]);
    }
    #pragma unroll
    for (int i=0;i<4;i++)
      #pragma unroll
      for (int j=0;j<4;j++)
        acc[i][j] = __builtin_amdgcn_mfma_f32_16x16x32_bf16(af[i], bg[j], acc[i][j], 0, 0, 0);
  }

  float* Sb = S + (size_t)b*NN*NN;
  unsigned short* Kb = Kg + (size_t)b*NN*NN;
  #pragma unroll
  for (int i=0;i<4;i++){
    #pragma unroll
    for (int j=0;j<4;j++){
      int n = nbase + wn*64 + j*16 + l16;
      #pragma unroll
      for (int v=0;v<4;v++){
        int m = mbase + wm*64 + i*16 + quad*4 + v;
        float sv = acc[i][j][v];
        Sb[(size_t)m*NN + n] = sv;
        float sc = fminf(fmaxf(sv, -3.f), 3.f);
        Kb[(size_t)m*NN + n] = f2bf(__expf(5.f*sc));
      }
    }
  }
}

// -------- L2-local exchange primitives (fast path) --------
// store_l2: plain store (CDNA vector L1 is write-through -> lands in the
// XCD's L2, which is shared by all CUs of that XCD).
// poll8: 8 loads with sc0 (L1-bypass -> reads the shared L2).
__device__ __forceinline__ void store_l2(float* p, float x){
  __hip_atomic_store(p, x, __ATOMIC_RELAXED, __HIP_MEMORY_SCOPE_WORKGROUP);
}

__device__ __forceinline__ bool poll8(const float* base, unsigned voff, float thr, float& sum){
  float x0,x1,x2,x3,x4,x5,x6,x7; unsigned a;
  asm volatile(
    "v_mov_b32 %8, %9\n\t"
    "global_load_dword %0, %8, %10 sc0\n\t"
    "v_add_u32 %8, 0x1000, %8\n\t"
    "global_load_dword %1, %8, %10 sc0\n\t"
    "v_add_u32 %8, 0x1000, %8\n\t"
    "global_load_dword %2, %8, %10 sc0\n\t"
    "v_add_u32 %8, 0x1000, %8\n\t"
    "global_load_dword %3, %8, %10 sc0\n\t"
    "v_add_u32 %8, 0x1000, %8\n\t"
    "global_load_dword %4, %8, %10 sc0\n\t"
    "v_add_u32 %8, 0x1000, %8\n\t"
    "global_load_dword %5, %8, %10 sc0\n\t"
    "v_add_u32 %8, 0x1000, %8\n\t"
    "global_load_dword %6, %8, %10 sc0\n\t"
    "v_add_u32 %8, 0x1000, %8\n\t"
    "global_load_dword %7, %8, %10 sc0\n\t"
    "s_waitcnt vmcnt(0)"
    : "=&v"(x0),"=&v"(x1),"=&v"(x2),"=&v"(x3),
      "=&v"(x4),"=&v"(x5),"=&v"(x6),"=&v"(x7),"=&v"(a)
    : "v"(voff), "s"((uint64_t)(uintptr_t)base)
    : "memory");
  bool ok = (x0>thr)&(x1>thr)&(x2>thr)&(x3>thr)&(x4>thr)&(x5>thr)&(x6>thr)&(x7>thr);
  sum = ((x0+x1)+(x2+x3))+((x4+x5)+(x6+x7));
  return ok;
}

__device__ __forceinline__ bool poll16(const float* base, int t, float thr, float& sum){
  float s0, s1;
  bool o0 = poll8(base, (unsigned)(t*4), thr, s0);
  bool o1 = poll8(base, (unsigned)(t*4) + 8u*4096u, thr, s1);
  sum = s0 + s1;
  return o0 & o1;
}

// ---------------- kernel 3: persistent Sinkhorn, K register-resident -------
// 256 blocks x 1024 threads. Rounds 0-3 measured: ANY agent-scope exchange
// protocol costs ~13 us/iter (coherence-point RT x 16-block skew); compute
// is ~2 us. Round 3's L2-local fast path never engaged because block->XCD
// placement was ASSUMED (blk%8), not measured.
//
// Round 4: measure placement with s_getreg(HW_REG_XCC_ID) [m09], then remap
// work so each batch's 16 blocks share one XCD (whose L2 IS coherent across
// its CUs):
//  1. every block publishes xcc to a 256-entry agent-scope map (write-once,
//     no preconditions -> spin-until-complete is deadlock-free; all 256
//     blocks co-resident: 256 CUs x 2048-thread capacity).
//  2. every block computes the SAME canonical permutation (stable sort by
//     (xcc, blk)); pos -> (batch=pos>>4, rb=pos&15). Bijective, consistent.
//     A batch is fast-ELIGIBLE iff its 16-slot window lies inside one XCD's
//     segment (true for interior batches at ~32 blocks/XCD, any dispatch).
//  3. eligible batches run the 2-phase visibility probe (30us timeouts);
//     verdicts exchanged agent-scope; all-16-pass -> L2-local exchange
//     (plain store + sc0 poll), else round-2 agent protocol (known-good).
// Rotation safety (both paths): each iteration's __syncthreads drains
// vmcnt, so zero-stores are acked/visible a full barrier-separated
// iteration before any poll can observe that buffer again.
__global__ __launch_bounds__(1024) void sinkhorn_kernel(
    const unsigned short* __restrict__ Kg, float* __restrict__ P,
    float* __restrict__ slots, unsigned* __restrict__ verdict,
    unsigned* __restrict__ xmap)
{
  __shared__ __align__(16) float v[NN];
  __shared__ __align__(16) float part[NN];
  __shared__ __align__(16) float u[64];
  __shared__ int bad;
  __shared__ int fastflag;
  __shared__ int sh_b, sh_rb, sh_elig;

  const int blk = blockIdx.x;
  const int t = threadIdx.x;
  const int w = t >> 6;      // wave id: column chunk for row phase
  const int l = t & 63;      // lane: row id for row phase

  // ---------- placement measurement + canonical remap ----------
  unsigned xcc;
  asm volatile("s_getreg_b32 %0, hwreg(HW_REG_XCC_ID)" : "=s"(xcc));
  xcc &= 15u;
  if (t == 0){
    __hip_atomic_store(&xmap[blk], xcc + 1u,
                       __ATOMIC_RELAXED, __HIP_MEMORY_SCOPE_AGENT);
    for(;;){   // wait until all 256 published (write-once, guaranteed)
      bool done = true;
      for (int i=0;i<256;i++){
        if (__hip_atomic_load(&xmap[i], __ATOMIC_RELAXED,
                              __HIP_MEMORY_SCOPE_AGENT) == 0u){ done=false; break; }
      }
      if (done) break;
      __builtin_amdgcn_s_sleep(8);
    }
    int cnt[16]; for (int x=0;x<16;x++) cnt[x]=0;
    int pos = 0;
    for (int i=0;i<256;i++){
      unsigned x = (__hip_atomic_load(&xmap[i], __ATOMIC_RELAXED,
                                      __HIP_MEMORY_SCOPE_AGENT) - 1u) & 15u;
      cnt[x]++;
      if (x < xcc || (x == xcc && i < blk)) pos++;
    }
    int batch = pos >> 4, rb = pos & 15;
    int pre = 0, elig = 0, lo = batch*16, hi = lo+16;
    for (int x=0;x<16;x++){ if (pre <= lo && hi <= pre + cnt[x]) elig = 1; pre += cnt[x]; }
    sh_b = batch; sh_rb = rb; sh_elig = elig;
  }
  __syncthreads();
  const int b  = sh_b;
  const int rb = sh_rb;
  const int eligible = sh_elig;

  const unsigned short* Kgb = Kg + ((size_t)(b*NN + rb*64))*NN;

  // column slice: rows 0..63 of column t, packed 2 rows per u32
  unsigned kcol[32];
  #pragma unroll
  for (int k=0;k<32;k++){
    unsigned lo = Kgb[(size_t)(2*k)*NN + t];
    unsigned hi = Kgb[(size_t)(2*k+1)*NN + t];
    kcol[k] = lo | (hi << 16);
  }
  // row slice: row l, cols w*64 .. w*64+63
  unsigned krow[32];
  {
    const uint4* rs = (const uint4*)(Kgb + (size_t)l*NN + w*64);
    #pragma unroll
    for (int k=0;k<8;k++){
      uint4 q4 = rs[k];
      krow[4*k+0]=q4.x; krow[4*k+1]=q4.y; krow[4*k+2]=q4.z; krow[4*k+3]=q4.w;
    }
  }
  v[t] = 1.0f;                      // v0 = 1 (global normalize cancels)

  // ---------- runtime probe of L2-local cross-block visibility ----------
  float* sl_b = slots + (size_t)b*4*16*NN;       // [4 bufs][16 blocks][NN]
  float* probe_base = sl_b + (size_t)3*16*NN;    // buffer 3 = probe region
  {
    bool ok = false;
    if (eligible){
      float dum;
      store_l2(probe_base + (size_t)rb*NN + t, 1.0f);
      unsigned long long dl = __builtin_amdgcn_s_memrealtime() + 3000ull; // ~30us
      for(;;){
        ok = poll16(probe_base, t, 0.5f, dum);
        if (ok) break;
        if (__builtin_amdgcn_s_memrealtime() > dl) break;
        __builtin_amdgcn_s_sleep(1);
      }
      if (ok){  // phase 2: update must be seen through a previously-read line
        store_l2(probe_base + (size_t)rb*NN + t, 2.0f);
        dl = __builtin_amdgcn_s_memrealtime() + 3000ull;
        for(;;){
          if (poll16(probe_base, t, 1.5f, dum)) break;
          if (__builtin_amdgcn_s_memrealtime() > dl){ ok = false; break; }
          __builtin_amdgcn_s_sleep(1);
        }
      }
    }
    if (t == 0) bad = 0;
    __syncthreads();
    if (!ok) bad = 1;                 // benign LDS race, all write 1
    __syncthreads();
    if (t == 0){
      unsigned my = bad ? 2u : 1u;    // 1 = fast ok, 2 = fail (0 = absent)
      __hip_atomic_store(&verdict[b*16 + rb], my,
                         __ATOMIC_RELAXED, __HIP_MEMORY_SCOPE_AGENT);
      int f = 1;
      for(;;){
        bool pending = false; f = 1;
        for (int p=0;p<16;p++){
          unsigned x = __hip_atomic_load(&verdict[b*16 + p],
                                         __ATOMIC_RELAXED, __HIP_MEMORY_SCOPE_AGENT);
          if (x == 0u){ pending = true; break; }
          if (x != 1u) f = 0;
        }
        if (!pending) break;
        __builtin_amdgcn_s_sleep(8);
      }
      fastflag = f;
    }
    __syncthreads();
  }
  const bool fastf = (fastflag != 0);

  const float4* v4 = (const float4*)v;
  const float4* u4 = (const float4*)u;
  float* my_slot = sl_b + (size_t)rb*NN + t;     // + buf*16*NN

  int buf = 0;
  float vt = 1.0f;
  for (int it = 0; it < 101; it++){     // 100 scan steps + 1 final step
    // phase A: u = 1/(K v). Wave w covers cols [64w,64w+64) of row l.
    float rsum = 0.f;
    #pragma unroll
    for (int k=0;k<16;k++){
      float4 vv = v4[w*16 + k];         // wave-uniform -> broadcast, no conflict
      unsigned ka = krow[2*k], kb = krow[2*k+1];
      rsum += bflo(ka)*vv.x + bfhi(ka)*vv.y + bflo(kb)*vv.z + bfhi(kb)*vv.w;
    }
    part[w*64 + l] = rsum;              // bank = l%32 -> 2-way, free
    __syncthreads();
    if (t < 64){
      float s = 0.f;
      #pragma unroll
      for (int q=0;q<16;q++) s += part[q*64 + t];
      u[t] = 1.0f / s;
    }
    __syncthreads();
    // phase B: column partial over our 64 rows (u reads broadcast)
    float csum = 0.f;
    #pragma unroll
    for (int k=0;k<16;k++){
      float4 uu = u4[k];
      unsigned ka = kcol[2*k], kb = kcol[2*k+1];
      csum += bflo(ka)*uu.x + bfhi(ka)*uu.y + bflo(kb)*uu.z + bfhi(kb)*uu.w;
    }
    float cs;
    int prev = (buf == 0) ? 2 : buf - 1;
    if (fastf){
      // L2-local exchange: plain store + sc0 poll (data-as-flag)
      store_l2(my_slot + (size_t)buf*16*NN, csum);
      const float* base = sl_b + (size_t)buf*16*NN;
      for(;;){
        if (poll16(base, t, 0.0f, cs)) break;
        __builtin_amdgcn_s_sleep(1);
      }
      store_l2(my_slot + (size_t)prev*16*NN, 0.f);
    } else {
      // agent-scope fallback (round-2 protocol, always correct)
      __hip_atomic_store(my_slot + (size_t)buf*16*NN, csum,
                         __ATOMIC_RELAXED, __HIP_MEMORY_SCOPE_AGENT);
      const float* base = sl_b + (size_t)buf*16*NN + t;
      for (;;){
        float s0 = 0.f; bool ok = true;
        #pragma unroll
        for (int p=0;p<16;p++){
          float x = __hip_atomic_load(base + (size_t)p*NN,
                                      __ATOMIC_RELAXED, __HIP_MEMORY_SCOPE_AGENT);
          ok &= (x != 0.f);
          s0 += x;
        }
        if (ok){ cs = s0; break; }
        __builtin_amdgcn_s_sleep(1);
      }
      __hip_atomic_store(my_slot + (size_t)prev*16*NN, 0.f,
                         __ATOMIC_RELAXED, __HIP_MEMORY_SCOPE_AGENT);
    }
    vt = 1.0f / cs;
    v[t] = vt;
    buf = (buf == 2) ? 0 : buf + 1;
    __syncthreads();
  }

  // epilogue: P[row][t] = u[row]*K[row][t]*v[t]  (overwrites K overlay; safe)
  float* Pb = P + ((size_t)(b*NN + rb*64))*NN;
  #pragma unroll
  for (int k=0;k<16;k++){
    float4 uu = u4[k];
    unsigned ka = kcol[2*k], kb = kcol[2*k+1];
    Pb[(size_t)(4*k+0)*NN + t] = bflo(ka)*uu.x*vt;
    Pb[(size_t)(4*k+1)*NN + t] = bfhi(ka)*uu.y*vt;
    Pb[(size_t)(4*k+2)*NN + t] = bflo(kb)*uu.z*vt;
    Pb[(size_t)(4*k+3)*NN + t] = bfhi(kb)*uu.w*vt;
  }
}

extern "C" void kernel_launch(void* const* d_in, const int* in_sizes, int n_in,
                              void* d_out, int out_size, void* d_ws, size_t ws_size,
                              hipStream_t stream)
{
  const float* fA = (const float*)d_in[0];
  const float* fB = (const float*)d_in[1];
  float* Pout = (float*)d_out;                       // outputs: [P | Sij]
  float* Sout = Pout + (size_t)NB*NN*NN;
  unsigned short* Kg = (unsigned short*)d_out;       // bf16 K overlays P region

  unsigned short* Abf = (unsigned short*)d_ws;                          // 8 MB
  unsigned short* Bbf = Abf + (size_t)NB*NN*ND;                         // 8 MB
  float* slots = (float*)((char*)d_ws + (size_t)16*1024*1024);          // 4 MB
  unsigned* verdict = (unsigned*)(slots + (size_t)NB*4*16*NN);          // 1 KB
  unsigned* xmap = verdict + NB*16;                                     // 1 KB

  // zero slot buffers (3 exchange + 1 probe) + verdicts + xcd map
  hipMemsetAsync(slots, 0, (size_t)NB*4*16*NN*4 + (size_t)NB*16*4 + 256*4, stream);
  norm_cast_kernel<<<dim3(8192), dim3(256), 0, stream>>>(fA, fB, Abf, Bbf);
  gemm_exp_kernel<<<dim3(8,8,NB), dim3(256), 0, stream>>>(Abf, Bbf, Sout, Kg);
  sinkhorn_kernel<<<dim3(256), dim3(1024), 0, stream>>>(Kg, Pout, slots, verdict, xmap);
}